// Round 8
// baseline (980.569 us; speedup 1.0000x reference)
//
#include <hip/hip_runtime.h>

#define Bsz  256
#define Tlen 2048
#define Hdim 128

typedef __fp16 hf2 __attribute__((ext_vector_type(2)));
typedef __fp16 hf8 __attribute__((ext_vector_type(8)));
typedef float  f32x4 __attribute__((ext_vector_type(4)));

// Raw-HW transcendentals (VOP1, ~1 ulp). R12-verified win.
__device__ __forceinline__ float fexp2_(float x) {
    float r; asm("v_exp_f32 %0, %1" : "=v"(r) : "v"(x)); return r;
}
__device__ __forceinline__ float frcp_(float x) {
    float r; asm("v_rcp_f32 %0, %1" : "=v"(r) : "v"(x)); return r;
}

// 16-lane-row sum via DPP rotate-accumulate (VALU only, no LDS pipe).
// quad_perm for the 2 cheap levels, row_ror for the 4/8 strides.
__device__ __forceinline__ float row16_sum(float v) {
    int vi, ri;
    vi = __builtin_bit_cast(int, v);
    ri = __builtin_amdgcn_update_dpp(0, vi, 0xB1, 0xf, 0xf, true); // quad_perm[1,0,3,2]
    v += __builtin_bit_cast(float, ri);
    vi = __builtin_bit_cast(int, v);
    ri = __builtin_amdgcn_update_dpp(0, vi, 0x4E, 0xf, 0xf, true); // quad_perm[2,3,0,1]
    v += __builtin_bit_cast(float, ri);
    vi = __builtin_bit_cast(int, v);
    ri = __builtin_amdgcn_update_dpp(0, vi, 0x124, 0xf, 0xf, true); // row_ror:4
    v += __builtin_bit_cast(float, ri);
    vi = __builtin_bit_cast(int, v);
    ri = __builtin_amdgcn_update_dpp(0, vi, 0x128, 0xf, 0xf, true); // row_ror:8
    v += __builtin_bit_cast(float, ri);
    return v;   // every lane in the 16-lane row holds the row sum
}

// pack 8 consecutive f32 into a v8f16 MFMA fragment slice
__device__ __forceinline__ hf8 pack8(const float* p) {
    union { hf2 h2[4]; hf8 h8; } u;
    u.h2[0] = __builtin_amdgcn_cvt_pkrtz(p[0], p[1]);
    u.h2[1] = __builtin_amdgcn_cvt_pkrtz(p[2], p[3]);
    u.h2[2] = __builtin_amdgcn_cvt_pkrtz(p[4], p[5]);
    u.h2[3] = __builtin_amdgcn_cvt_pkrtz(p[6], p[7]);
    return u.h8;
}
__device__ __forceinline__ hf8 bch8(float4 v) { return __builtin_bit_cast(hf8, v); }

#define MFMA(D, A, B) D = __builtin_amdgcn_mfma_f32_16x16x32_f16(A, B, D, 0, 0, 0)

struct Smem {
    float  x[Tlen];       // staged input row
    float  xh[Tlen];      // staged xh outputs
    __fp16 h[2][Hdim];    // double-buffered hidden state (f16)
    float  fcp[2][8];     // double-buffered per-wave fc partials
};

// grid = 256 blocks (1 batch row each), block = 512 threads (8 waves).
// R31 = R30 champion (split-K 8-chain, setprio antiphase, bias-seeded C,
// uniform-A, weights AGPR-native, one barrier/step) MINUS the fc MFMA
// chain (16 -> 12 MFMA/wave), fc computed one step early on the VALU.
// R30 post-mortem: MFMA busy = 563 cyc for 128 MFMA/CU = 4.4 cyc each =
// the m06 CU pipe rate -> the MFMA window is PIPE-THROUGHPUT-bound
// (R29: +128 MFMAs cost +4.97 each; R27: 96 MFMAs ran at 4.1 each).
// Cutting count is the only remaining lever; fc is 25% of count for a
// 16x-redundant scalar dot. R27 tried this and lost to handoff placement
// (no setprio/split-K then); here the handoff is engineered for the
// champion's overlap structure:
//  - tail: pw = wfc*hn (1 mul) -> h ds_write issued -> DPP tree (~35 cyc,
//    executes DURING the h-write lgkm drain) -> lane0 fcp write -> barrier.
//  - early: 2 uniform b128 fcp reads (issued with A-reads) + 8-add tree;
//    cur/pr/pz/an now depend on NO MFMA (split-K freed the early path).
//  - numerics: fc from unrounded f32 hn (closer to f32 reference than
//    the old f16 MFMA path); verified in R27, absmax 0.0009765625.
// Session ledger: R24 fc->VALU-in-step -21% | R25 reorder flat | R26 diet
// flat | R27 fc-early (no setprio/splitK) -5% | R28 setprio +4% |
// R29 2-row -61% | R30 split-K +1.7% (878.9 champ).
// Prediction: MFMA busy 563->466, dur ~800-840us. If flat: all terms at
// structural minimum -> ROOFLINE.
// Layouts (R18-R21 HW-verified): B: lane l reg j = W[tile*16+(l&15)]
// [c*32+(l>>4)*8+j]; D: col = lane&15, reg 0 valid on all lanes (uniform A).
__global__ __launch_bounds__(512, 2)
void rnn_imp_kernel(const float* __restrict__ x,     // [B, T] (I=1)
                    const float* __restrict__ Wih,   // [384]
                    const float* __restrict__ Whh,   // [384, 128] gate-major (r,z,n)
                    const float* __restrict__ bih,   // [384]
                    const float* __restrict__ bhh,   // [384]
                    const float* __restrict__ Wfc,   // [128]
                    const float* __restrict__ bfc,   // [1]
                    float* __restrict__ out_newin,   // [T, B]
                    float* __restrict__ out_pred)    // [B, T-1]
{
    __shared__ __align__(128) Smem sm;

    const int tid  = threadIdx.x;
    const int b    = blockIdx.x;
    const int wave = tid >> 6;
    const int lane = tid & 63;
    const int m    = lane & 15;      // B/D column = unit-in-tile
    const int q    = lane >> 4;      // k-subchunk

    // stage x row (coalesced)
    for (int i = tid; i < Tlen; i += 512) sm.x[i] = x[b * Tlen + i];

    // ---- B fragments: W^T tiles (consumed only by MFMA -> AGPR-native) ----
    const int r0 = wave * 16 + m;            // unit row, gate r
    const int r1 = r0 + 128;                 // gate z
    const int r2 = r0 + 256;                 // gate n
    const int ko = q * 8;
    hf8 Br0, Br1, Br2, Br3, Bz0, Bz1, Bz2, Bz3, Bn0, Bn1, Bn2, Bn3;
    Br0 = pack8(Whh + r0 * Hdim + 0  + ko);  Br1 = pack8(Whh + r0 * Hdim + 32 + ko);
    Br2 = pack8(Whh + r0 * Hdim + 64 + ko);  Br3 = pack8(Whh + r0 * Hdim + 96 + ko);
    Bz0 = pack8(Whh + r1 * Hdim + 0  + ko);  Bz1 = pack8(Whh + r1 * Hdim + 32 + ko);
    Bz2 = pack8(Whh + r1 * Hdim + 64 + ko);  Bz3 = pack8(Whh + r1 * Hdim + 96 + ko);
    Bn0 = pack8(Whh + r2 * Hdim + 0  + ko);  Bn1 = pack8(Whh + r2 * Hdim + 32 + ko);
    Bn2 = pack8(Whh + r2 * Hdim + 64 + ko);  Bn3 = pack8(Whh + r2 * Hdim + 96 + ko);

    // gate constants for this lane's column unit (valid on all lanes)
    const int ug = wave * 16 + m;
    const float wih_r = Wih[ug], wih_z = Wih[ug + 128], wih_n = Wih[ug + 256];
    const float bb_r = bih[ug]       + bhh[ug];
    const float bb_z = bih[ug + 128] + bhh[ug + 128];
    const float bi_n = bih[ug + 256];
    const float bh_n = bhh[ug + 256];
    const float bfc0 = bfc[0];
    const float wfc_u = Wfc[ug];             // f32 Wfc for the early fc partial

    // pre-scaled constants: fold log2e factors out of the per-step chain
    const float kNL2E = -1.44269504f;            // -log2(e)
    const float kP2L2E = 2.88539008f;            // 2*log2(e)
    const float wr_s  = kNL2E * wih_r;
    const float wz_s  = kNL2E * wih_z;
    const float wn_s  = kP2L2E * wih_n;
    const float bn_s  = kP2L2E * bi_n;
    // bias-seeded C operands for the LOW half-chains; zero for HIGH halves.
    const f32x4 C_R = {bb_r, bb_r, bb_r, bb_r};
    const f32x4 C_Z = {bb_z, bb_z, bb_z, bb_z};
    const f32x4 C_N = {bh_n, bh_n, bh_n, bh_n};
    const f32x4 C_0 = {0.0f, 0.0f, 0.0f, 0.0f};

    __syncthreads();                         // sm.x visible

    // ---- peeled t = 0: h = 0 => D = C-seed exactly; pure VALU ----
    float h_old;
    {
        float x0 = sm.x[0];
        float pr = wr_s * x0;
        float pz = wz_s * x0;
        float an = fmaf(wn_s, x0, bn_s);
        float r  = frcp_(1.0f + fexp2_(fmaf(kNL2E, bb_r, pr)));
        float z  = frcp_(1.0f + fexp2_(fmaf(kNL2E, bb_z, pz)));
        float rs = kP2L2E * r;
        float np = frcp_(fexp2_(fmaf(rs, bh_n, an)) + 1.0f);
        float w  = 1.0f - z;
        float hn = fmaf(-2.0f * w, np, w);   // hz = fma(z, 0, w) = w exactly
        h_old = hn;
        if (lane < 16) sm.h[1][ug] = (__fp16)hn;
        float pw = row16_sum(wfc_u * hn);    // fc partial for step 1
        if (lane == 0) sm.fcp[1][wave] = pw;
        // sm.xh[0] never consumed (out_pred uses xh[1..]; newin at i=0 is raw x)
    }
    __syncthreads();

#pragma unroll 1
    for (int t = 1; t < Tlen; ++t) {
        // A fragments + fc partials + xt: all LDS reads issued up front;
        // fcp/x are uniform-address (broadcast), latency overlaps A-reads.
        const float4* hp = (const float4*)sm.h[t & 1];
        hf8 A0 = bch8(hp[0 * 4 + q]);
        hf8 A1 = bch8(hp[1 * 4 + q]);
        hf8 A2 = bch8(hp[2 * 4 + q]);
        hf8 A3 = bch8(hp[3 * 4 + q]);
        const float4* fp = (const float4*)sm.fcp[t & 1];
        float4 pp0 = fp[0];
        float4 pp1 = fp[1];
        float xt = sm.x[t];

        __builtin_amdgcn_s_setprio(1);

        // 6 independent half-K chains x 2 MFMAs (fc chain deleted).
        // L chains: A0/A1 (k 0..63); H chains: A2/A3 (k 64..127).
        f32x4 D0L = __builtin_amdgcn_mfma_f32_16x16x32_f16(A0, Br0, C_R, 0, 0, 0);
        f32x4 D1L = __builtin_amdgcn_mfma_f32_16x16x32_f16(A0, Bz0, C_Z, 0, 0, 0);
        f32x4 D2L = __builtin_amdgcn_mfma_f32_16x16x32_f16(A0, Bn0, C_N, 0, 0, 0);
        f32x4 D0H = __builtin_amdgcn_mfma_f32_16x16x32_f16(A2, Br2, C_0, 0, 0, 0);
        f32x4 D1H = __builtin_amdgcn_mfma_f32_16x16x32_f16(A2, Bz2, C_0, 0, 0, 0);
        f32x4 D2H = __builtin_amdgcn_mfma_f32_16x16x32_f16(A2, Bn2, C_0, 0, 0, 0);
        MFMA(D0L, A1, Br1);                  // D0L complete
        MFMA(D0H, A3, Br3);                  // D0H complete

        // xh from the previous step's partials: NO MFMA dependency at all
        float xh  = (((pp0.x + pp0.y) + (pp0.z + pp0.w)) +
                     ((pp1.x + pp1.y) + (pp1.z + pp1.w))) + bfc0;
        float cur = (xt == 128.0f) ? xh : xt;
        float pr  = wr_s * cur;
        float pz  = wz_s * cur;
        float an  = fmaf(wn_s, cur, bn_s);
        float g0  = D0L[0] + D0H[0];
        float r   = frcp_(1.0f + fexp2_(fmaf(kNL2E, g0, pr)));
        float rs  = kP2L2E * r;              // hoisted off the D2->hn path

        MFMA(D1L, A1, Bz1);                  // D1L complete
        MFMA(D2L, A1, Bn1);                  // D2L complete
        MFMA(D1H, A3, Bz3);                  // D1H complete
        MFMA(D2H, A3, Bn3);                  // D2H complete

        __builtin_amdgcn_s_setprio(0);       // tail runs at low priority

        // gates: unpredicated on all 64 lanes (q-copies compute identical hn)
        float g1  = D1L[0] + D1H[0];
        float g2  = D2L[0] + D2H[0];
        float z   = frcp_(1.0f + fexp2_(fmaf(kNL2E, g1, pz)));
        float np  = frcp_(fexp2_(fmaf(rs, g2, an)) + 1.0f);     // n = 1 - 2*np
        float w   = 1.0f - z;
        float m2w = -2.0f * w;               // parallel to hz, off the chain
        float hz  = fmaf(z, h_old, w);
        float hn  = fmaf(m2w, np, hz);       // (1-z)*n + z*h
        h_old = hn;

        // h-write FIRST (its lgkm drain overlaps the DPP tree below)
        if (lane < 16) sm.h[(t + 1) & 1][ug] = (__fp16)hn;
        if (tid == 0)  sm.xh[t] = xh;

        // next step's fc partial: DPP rotate-reduce over the m-group
        float pw = row16_sum(wfc_u * hn);
        if (lane == 0) sm.fcp[(t + 1) & 1][wave] = pw;
        __syncthreads();
    }

    // bulk flush; cur reconstructed from pristine x + xh
    for (int i = tid; i < Tlen; i += 512) {
        float xv = sm.x[i];
        float cv = ((xv == 128.0f) && (i != 0)) ? sm.xh[i] : xv;
        out_newin[i * Bsz + b] = cv;
    }
    for (int i = tid; i < Tlen - 1; i += 512)
        out_pred[b * (Tlen - 1) + i] = sm.xh[i + 1];
}

extern "C" void kernel_launch(void* const* d_in, const int* in_sizes, int n_in,
                              void* d_out, int out_size, void* d_ws, size_t ws_size,
                              hipStream_t stream) {
    const float* x   = (const float*)d_in[0];
    const float* Wih = (const float*)d_in[1];
    const float* Whh = (const float*)d_in[2];
    const float* bih = (const float*)d_in[3];
    const float* bhh = (const float*)d_in[4];
    const float* Wfc = (const float*)d_in[5];
    const float* bfc = (const float*)d_in[6];

    float* out_newin = (float*)d_out;                 // [T*B] = 524288
    float* out_pred  = out_newin + Tlen * Bsz;        // [B*(T-1)] = 524032

    rnn_imp_kernel<<<Bsz, 512, 0, stream>>>(x, Wih, Whh, bih, bhh, Wfc, bfc,
                                            out_newin, out_pred);
}

// Round 10
// 898.034 us; speedup vs baseline: 1.0919x; 1.0919x over previous
//
#include <hip/hip_runtime.h>

#define Bsz  256
#define Tlen 2048
#define Hdim 128

typedef __fp16 hf2 __attribute__((ext_vector_type(2)));
typedef __fp16 hf8 __attribute__((ext_vector_type(8)));
typedef float  f32x4 __attribute__((ext_vector_type(4)));

// Raw-HW transcendentals (VOP1, ~1 ulp). R12-verified win.
__device__ __forceinline__ float fexp2_(float x) {
    float r; asm("v_exp_f32 %0, %1" : "=v"(r) : "v"(x)); return r;
}
__device__ __forceinline__ float frcp_(float x) {
    float r; asm("v_rcp_f32 %0, %1" : "=v"(r) : "v"(x)); return r;
}

// pack 8 consecutive f32 into a v8f16 MFMA fragment slice
__device__ __forceinline__ hf8 pack8(const float* p) {
    union { hf2 h2[4]; hf8 h8; } u;
    u.h2[0] = __builtin_amdgcn_cvt_pkrtz(p[0], p[1]);
    u.h2[1] = __builtin_amdgcn_cvt_pkrtz(p[2], p[3]);
    u.h2[2] = __builtin_amdgcn_cvt_pkrtz(p[4], p[5]);
    u.h2[3] = __builtin_amdgcn_cvt_pkrtz(p[6], p[7]);
    return u.h8;
}
__device__ __forceinline__ hf8 bch8(float4 v) { return __builtin_bit_cast(hf8, v); }

#define MFMA3(A, B, C) __builtin_amdgcn_mfma_f32_16x16x32_f16(A, B, C, 0, 0, 0)

struct Smem {
    float  x[Tlen];       // staged input row
    float  xh[Tlen];      // staged xh outputs
    __fp16 h[2][Hdim];    // double-buffered hidden state (f16)
};

// grid = 256 blocks (1 batch row each), block = 512 threads (8 waves).
// R32 = R30 champion, split-K deepened 8 -> 16 chains (one MFMA each,
// fully independent) with COMPLETION-ORDERED issue + z-last algebra.
// (Resubmitted unchanged after R9's GPUAcquisitionTimeout — no data.)
// R31 post-mortem (3rd confirmation): the MFMA window has slack; the
// post-last-MFMA serial segment does not — anything added there costs
// 1:1, anything removed from the window is absorbed. R30's last chains
// (z/n) close at issue positions 13-16, so their results land at the END
// of the ~600-cyc FIFO drain and the full z/np->hn chain (~80+ cyc) runs
// after it. Fix:
//  - 16 quarter-K chains (K=32 each), zero intra-chain deps -> max-rate
//    issue; 12 closing adds (tree) hidden inside the drain.
//  - Issue order = tail need order: fc (cur, ~pos 4) -> r (~8) ->
//    n-input (~12) -> z LAST.
//  - hn = fmaf(z, h_old - n, n): n, h_old-n precomputed inside the
//    window; exactly ONE fma between the last MFMA result and hn.
//  - Numerics: K-sum reassociation only; absmax unchanged.
// Session ledger: R24 fc->VALU -21% | R25 reorder flat | R26 diet flat |
// R27 fc-early -5% | R28 setprio +4% | R29 2-row -61% | R30 split-K8
// +1.7% (878.9 champ) | R31 fc-early-on-champ -12%.
// Prediction: dur ~800-840us, MfmaUtil ~56-60%. If flat: ~300-cyc fixed
// hazard/sync term -> structural floor, declare roofline.
// Layouts (R18-R21 HW-verified): B: lane l reg j = W[tile*16+(l&15)]
// [c*32+(l>>4)*8+j]; D: col = lane&15, reg 0 valid on all lanes (uniform A).
__global__ __launch_bounds__(512, 2)
void rnn_imp_kernel(const float* __restrict__ x,     // [B, T] (I=1)
                    const float* __restrict__ Wih,   // [384]
                    const float* __restrict__ Whh,   // [384, 128] gate-major (r,z,n)
                    const float* __restrict__ bih,   // [384]
                    const float* __restrict__ bhh,   // [384]
                    const float* __restrict__ Wfc,   // [128]
                    const float* __restrict__ bfc,   // [1]
                    float* __restrict__ out_newin,   // [T, B]
                    float* __restrict__ out_pred)    // [B, T-1]
{
    __shared__ __align__(128) Smem sm;

    const int tid  = threadIdx.x;
    const int b    = blockIdx.x;
    const int wave = tid >> 6;
    const int lane = tid & 63;
    const int m    = lane & 15;      // B/D column = unit-in-tile
    const int q    = lane >> 4;      // k-subchunk

    // stage x row (coalesced)
    for (int i = tid; i < Tlen; i += 512) sm.x[i] = x[b * Tlen + i];

    // ---- B fragments: W^T tiles (consumed only by MFMA -> AGPR-native) ----
    const int r0 = wave * 16 + m;            // unit row, gate r
    const int r1 = r0 + 128;                 // gate z
    const int r2 = r0 + 256;                 // gate n
    const int ko = q * 8;
    hf8 Br0, Br1, Br2, Br3, Bz0, Bz1, Bz2, Bz3,
        Bn0, Bn1, Bn2, Bn3, Bf0, Bf1, Bf2, Bf3;
    Br0 = pack8(Whh + r0 * Hdim + 0  + ko);  Br1 = pack8(Whh + r0 * Hdim + 32 + ko);
    Br2 = pack8(Whh + r0 * Hdim + 64 + ko);  Br3 = pack8(Whh + r0 * Hdim + 96 + ko);
    Bz0 = pack8(Whh + r1 * Hdim + 0  + ko);  Bz1 = pack8(Whh + r1 * Hdim + 32 + ko);
    Bz2 = pack8(Whh + r1 * Hdim + 64 + ko);  Bz3 = pack8(Whh + r1 * Hdim + 96 + ko);
    Bn0 = pack8(Whh + r2 * Hdim + 0  + ko);  Bn1 = pack8(Whh + r2 * Hdim + 32 + ko);
    Bn2 = pack8(Whh + r2 * Hdim + 64 + ko);  Bn3 = pack8(Whh + r2 * Hdim + 96 + ko);
    // Wfc in ALL columns: every lane's fc reg 0 = xp
    Bf0 = pack8(Wfc + 0  + ko);  Bf1 = pack8(Wfc + 32 + ko);
    Bf2 = pack8(Wfc + 64 + ko);  Bf3 = pack8(Wfc + 96 + ko);

    // gate constants for this lane's column unit (valid on all lanes)
    const int ug = wave * 16 + m;
    const float wih_r = Wih[ug], wih_z = Wih[ug + 128], wih_n = Wih[ug + 256];
    const float bb_r = bih[ug]       + bhh[ug];
    const float bb_z = bih[ug + 128] + bhh[ug + 128];
    const float bi_n = bih[ug + 256];
    const float bh_n = bhh[ug + 256];
    const float bfc0 = bfc[0];

    // pre-scaled constants: fold log2e factors out of the per-step chain
    const float kNL2E = -1.44269504f;            // -log2(e)
    const float kP2L2E = 2.88539008f;            // 2*log2(e)
    const float wr_s  = kNL2E * wih_r;
    const float wz_s  = kNL2E * wih_z;
    const float wn_s  = kP2L2E * wih_n;
    const float bn_s  = kP2L2E * bi_n;
    // bias-seeded C operands, one per gate (quarter 0); zero elsewhere.
    const f32x4 C_R = {bb_r, bb_r, bb_r, bb_r};
    const f32x4 C_Z = {bb_z, bb_z, bb_z, bb_z};
    const f32x4 C_N = {bh_n, bh_n, bh_n, bh_n};
    const f32x4 C_F = {bfc0, bfc0, bfc0, bfc0};
    const f32x4 C_0 = {0.0f, 0.0f, 0.0f, 0.0f};

    __syncthreads();                         // sm.x visible

    // ---- peeled t = 0: h = 0 => D = C-seed exactly; pure VALU ----
    float h_old;
    {
        float x0 = sm.x[0];
        float pr = wr_s * x0;
        float pz = wz_s * x0;
        float an = fmaf(wn_s, x0, bn_s);
        float r  = frcp_(1.0f + fexp2_(fmaf(kNL2E, bb_r, pr)));
        float z  = frcp_(1.0f + fexp2_(fmaf(kNL2E, bb_z, pz)));
        float rs = kP2L2E * r;
        float np = frcp_(fexp2_(fmaf(rs, bh_n, an)) + 1.0f);
        float w  = 1.0f - z;
        float hn = fmaf(-2.0f * w, np, w);   // hz = fma(z, 0, w) = w exactly
        h_old = hn;
        if (lane < 16) sm.h[1][ug] = (__fp16)hn;
        // sm.xh[0] never consumed (out_pred uses xh[1..]; newin at i=0 is raw x)
    }
    __syncthreads();

#pragma unroll 1
    for (int t = 1; t < Tlen; ++t) {
        // A fragments: every row = h (uniform-address broadcast reads)
        const float4* hp = (const float4*)sm.h[t & 1];
        hf8 A0 = bch8(hp[0 * 4 + q]);
        hf8 A1 = bch8(hp[1 * 4 + q]);
        hf8 A2 = bch8(hp[2 * 4 + q]);
        hf8 A3 = bch8(hp[3 * 4 + q]);

        // xt early: LDS latency hides under the MFMA block
        float xt = sm.x[t];

        __builtin_amdgcn_s_setprio(1);

        // 16 independent quarter-K chains (1 MFMA each), issue ordered by
        // when the tail consumes them: fc -> r -> n -> z (z dead last).
        f32x4 P0 = MFMA3(A0, Bf0, C_F);
        f32x4 P1 = MFMA3(A1, Bf1, C_0);
        f32x4 P2 = MFMA3(A2, Bf2, C_0);
        f32x4 P3 = MFMA3(A3, Bf3, C_0);
        f32x4 R0 = MFMA3(A0, Br0, C_R);
        f32x4 R1 = MFMA3(A1, Br1, C_0);
        f32x4 R2 = MFMA3(A2, Br2, C_0);
        f32x4 R3 = MFMA3(A3, Br3, C_0);

        // fc ready earliest: cur + gate-input terms inside the drain window
        float xh  = (P0[0] + P1[0]) + (P2[0] + P3[0]);    // bfc0 pre-seeded
        float cur = (xt == 128.0f) ? xh : xt;
        if (tid == 0) sm.xh[t] = xh;         // store early, off the chain
        float pr  = wr_s * cur;
        float pz  = wz_s * cur;
        float an  = fmaf(wn_s, cur, bn_s);

        f32x4 N0 = MFMA3(A0, Bn0, C_N);
        f32x4 N1 = MFMA3(A1, Bn1, C_0);
        f32x4 N2 = MFMA3(A2, Bn2, C_0);
        f32x4 N3 = MFMA3(A3, Bn3, C_0);

        // r-gate: completes by ~issue position 8
        float g0 = (R0[0] + R1[0]) + (R2[0] + R3[0]);
        float r  = frcp_(1.0f + fexp2_(fmaf(kNL2E, g0, pr)));
        float rs = kP2L2E * r;

        f32x4 Z0 = MFMA3(A0, Bz0, C_Z);
        f32x4 Z1 = MFMA3(A1, Bz1, C_0);
        f32x4 Z2 = MFMA3(A2, Bz2, C_0);
        f32x4 Z3 = MFMA3(A3, Bz3, C_0);

        __builtin_amdgcn_s_setprio(0);

        // n-chain: inputs complete by ~position 12; runs under z's drain
        float g2 = (N0[0] + N1[0]) + (N2[0] + N3[0]);
        float np = frcp_(fexp2_(fmaf(rs, g2, an)) + 1.0f);
        float n_ = fmaf(-2.0f, np, 1.0f);    // n = 1 - 2*np
        float d_ = h_old - n_;

        // z-chain: the ONLY post-drain serial work (add-tree + sigmoid + 1 fma)
        float g1 = (Z0[0] + Z1[0]) + (Z2[0] + Z3[0]);
        float z  = frcp_(1.0f + fexp2_(fmaf(kNL2E, g1, pz)));
        float hn = fmaf(z, d_, n_);          // (1-z)*n + z*h
        h_old = hn;

        if (lane < 16) sm.h[(t + 1) & 1][ug] = (__fp16)hn;
        __syncthreads();
    }

    // bulk flush; cur reconstructed from pristine x + xh
    for (int i = tid; i < Tlen; i += 512) {
        float xv = sm.x[i];
        float cv = ((xv == 128.0f) && (i != 0)) ? sm.xh[i] : xv;
        out_newin[i * Bsz + b] = cv;
    }
    for (int i = tid; i < Tlen - 1; i += 512)
        out_pred[b * (Tlen - 1) + i] = sm.xh[i + 1];
}

extern "C" void kernel_launch(void* const* d_in, const int* in_sizes, int n_in,
                              void* d_out, int out_size, void* d_ws, size_t ws_size,
                              hipStream_t stream) {
    const float* x   = (const float*)d_in[0];
    const float* Wih = (const float*)d_in[1];
    const float* Whh = (const float*)d_in[2];
    const float* bih = (const float*)d_in[3];
    const float* bhh = (const float*)d_in[4];
    const float* Wfc = (const float*)d_in[5];
    const float* bfc = (const float*)d_in[6];

    float* out_newin = (float*)d_out;                 // [T*B] = 524288
    float* out_pred  = out_newin + Tlen * Bsz;        // [B*(T-1)] = 524032

    rnn_imp_kernel<<<Bsz, 512, 0, stream>>>(x, Wih, Whh, bih, bhh, Wfc, bfc,
                                            out_newin, out_pred);
}